// Round 9
// baseline (109.636 us; speedup 1.0000x reference)
//
#include <hip/hip_runtime.h>
#include <hip/hip_fp16.h>
#include <math.h>

#define TBINS   50000
#define NR      4
#define RBINS   12500          // TBINS / NR
#define EPSF    1e-7f
#define NPB     256            // partition blocks
#define NWV     16             // waves per partition block (1024 thr)
#define NSL     32             // pass slices (each covers NPB/NSL=8 part blocks)
#define NFB     50             // final blocks
#define GROUPB  1000           // bins per final block
#define PER_SLICE 256000       // u32 ab[TBINS] (200000) + u8 cnt[TBINS] (50000), padded

// ---- ws layout (byte offsets) ----
#define OFF_SCAL  0            // dbl[2]: [1]=log-sum accumulator
#define OFF_DONE  16           // int (k_final finalize ticket)
#define OFF_GSUM  64           // f32[NFB]
#define OFF_LRP   512          // f32[NPB]
#define OFF_NP    1536         // i32[NPB]
#define OFF_CNTS  4096         // u32[NPB*NWV*4]
#define OFF_PART  69632        // u32[NPB*NWV*4*WCH]

// ============ k_part: read raw once, pack+partition into per-(blk,wave,range) segments ============
__global__ __launch_bounds__(1024) void k_part(
        const float* __restrict__ lr, const int* __restrict__ tm,
        const int* __restrict__ ev, int N, int WCH,
        unsigned* __restrict__ part, unsigned* __restrict__ cnts,
        float* __restrict__ lrp, int* __restrict__ np,
        float* __restrict__ gsum, double* __restrict__ scal,
        int* __restrict__ done) {
    __shared__ float red_f[16];
    __shared__ int   red_i[16];
    const int b = blockIdx.x, tid = threadIdx.x;
    const int w = tid >> 6, lane = tid & 63;
    const unsigned long long lmask = (1ULL << lane) - 1ULL;

    // re-init cross-call state (replay-deterministic)
    if (b == 0) {
        if (tid < NFB) gsum[tid] = 0.f;
        if (tid == NFB)     scal[1] = 0.0;
        if (tid == NFB + 1) *done   = 0;
    }

    const int base0 = (b * NWV + w) * WCH;
    const unsigned seg0 = (unsigned)(b * NWV + w) * 4u;
    unsigned wc0 = 0, wc1 = 0, wc2 = 0, wc3 = 0;
    float l_lr = 0.f; int l_n = 0;

#define PART1(L, T, E, VALID) {                                           \
        float r_ = __expf(L);                                             \
        unsigned hb_ = (unsigned)__half_as_ushort(__float2half(r_));      \
        bool ve_ = (VALID) && ((E) != 0);                                 \
        if (ve_) { hb_ |= 0x8000u; l_lr += (L); l_n++; }                  \
        unsigned P_  = ((unsigned)(T) << 16) | hb_;                       \
        unsigned rg_ = ((unsigned)(T)) / 12500u;                          \
        { unsigned long long m_ = __ballot((VALID) && rg_ == 0u);         \
          if ((VALID) && rg_ == 0u)                                       \
              part[(size_t)(seg0 + 0u) * WCH + wc0 + (unsigned)__popcll(m_ & lmask)] = P_; \
          wc0 += (unsigned)__popcll(m_); }                                \
        { unsigned long long m_ = __ballot((VALID) && rg_ == 1u);         \
          if ((VALID) && rg_ == 1u)                                       \
              part[(size_t)(seg0 + 1u) * WCH + wc1 + (unsigned)__popcll(m_ & lmask)] = P_; \
          wc1 += (unsigned)__popcll(m_); }                                \
        { unsigned long long m_ = __ballot((VALID) && rg_ == 2u);         \
          if ((VALID) && rg_ == 2u)                                       \
              part[(size_t)(seg0 + 2u) * WCH + wc2 + (unsigned)__popcll(m_ & lmask)] = P_; \
          wc2 += (unsigned)__popcll(m_); }                                \
        { unsigned long long m_ = __ballot((VALID) && rg_ == 3u);         \
          if ((VALID) && rg_ == 3u)                                       \
              part[(size_t)(seg0 + 3u) * WCH + wc3 + (unsigned)__popcll(m_ & lmask)] = P_; \
          wc3 += (unsigned)__popcll(m_); }                                \
    }

    for (int it = 0; it < WCH; it += 256) {
        int idx = base0 + it + lane * 4;
        float4 l4 = {0.f, 0.f, 0.f, 0.f};
        int4   t4 = {0, 0, 0, 0};
        int4   e4 = {0, 0, 0, 0};
        if (idx + 3 < N) {
            l4 = *(const float4*)(lr + idx);
            t4 = *(const int4*)(tm + idx);
            e4 = *(const int4*)(ev + idx);
        } else if (idx < N) {
            float* lp = (float*)&l4; int* tp = (int*)&t4; int* ep = (int*)&e4;
            for (int k = 0; k < 4 && idx + k < N; ++k) {
                lp[k] = lr[idx + k]; tp[k] = tm[idx + k]; ep[k] = ev[idx + k];
            }
        }
        PART1(l4.x, t4.x, e4.x, (idx + 0) < N)
        PART1(l4.y, t4.y, e4.y, (idx + 1) < N)
        PART1(l4.z, t4.z, e4.z, (idx + 2) < N)
        PART1(l4.w, t4.w, e4.w, (idx + 3) < N)
    }

    if (lane == 0) {
        unsigned* c = cnts + seg0;
        c[0] = wc0; c[1] = wc1; c[2] = wc2; c[3] = wc3;
    }

    #pragma unroll
    for (int off = 32; off > 0; off >>= 1) {
        l_lr += __shfl_down(l_lr, off, 64);
        l_n  += __shfl_down(l_n,  off, 64);
    }
    if (lane == 0) { red_f[w] = l_lr; red_i[w] = l_n; }
    __syncthreads();
    if (tid == 0) {
        float s = 0.f; int c = 0;
        #pragma unroll
        for (int i = 0; i < NWV; ++i) { s += red_f[i]; c += red_i[i]; }
        lrp[b] = s; np[b] = c;
    }
}

// ============ k_pass: single-visit LDS histogram per (range, slice); also gsum partials ============
__global__ __launch_bounds__(1024) void k_pass(
        const unsigned* __restrict__ part, const unsigned* __restrict__ cnts,
        int WCH, char* __restrict__ slices, float* __restrict__ gsum) {
    __shared__ float    s_all[RBINS];
    __shared__ unsigned s_evcnt[RBINS];   // (count<<28) | fixed12.16(sum exp over events)
    const int bid = blockIdx.x;
    const int r = bid & 3, s = bid >> 2;
    const int rbase = r * RBINS;
    const int tid = threadIdx.x, w = tid >> 6, lane = tid & 63;

    for (int i = tid; i < RBINS; i += 1024) { s_all[i] = 0.f; s_evcnt[i] = 0u; }
    __syncthreads();

    // 128 segments feed this block: part-blocks [8s,8s+8) x 16 waves; wave w takes 8
    for (int sl = w; sl < 8 * NWV; sl += NWV) {
        int pb = 8 * s + (sl >> 4);
        int pw = sl & 15;
        unsigned seg = (unsigned)(pb * NWV + pw) * 4u + (unsigned)r;
        unsigned cnt = cnts[seg];
        const unsigned* sp = part + (size_t)seg * WCH;
        for (unsigned i = (unsigned)lane; i < cnt; i += 64u) {
            unsigned P = sp[i];
            unsigned rel = (P >> 16) - (unsigned)rbase;
            if (rel < (unsigned)RBINS) {
                float r_ = __half2float(__ushort_as_half((unsigned short)(P & 0x7FFFu)));
                atomicAdd(&s_all[rel], r_);
                if (P & 0x8000u) {
                    unsigned enc = (1u << 28) + (unsigned)(r_ * 65536.0f + 0.5f);
                    atomicAdd(&s_evcnt[rel], enc);
                }
            }
        }
    }
    __syncthreads();

    // flush: f16(all)|f16(ev) + u8 count
    char* sb = slices + (size_t)s * PER_SLICE;
    unsigned*      wab = (unsigned*)sb;
    unsigned char* wcq = (unsigned char*)(sb + 200000);
    for (int i = tid; i < RBINS; i += 1024) {
        float a = s_all[i];
        unsigned ec = s_evcnt[i];
        float e = (float)(ec & 0x0FFFFFFFu) * (1.0f / 65536.0f);
        wab[rbase + i] = (unsigned)__half_as_ushort(__float2half(a))
                       | ((unsigned)__half_as_ushort(__float2half(e)) << 16);
        wcq[rbase + i] = (unsigned char)(ec >> 28);
    }

    // group partials for the prefix base, from f16-round-tripped values (consistency)
    int g0 = rbase / GROUPB;                       // 13 groups touched per range
    int gN = (rbase + RBINS - 1) / GROUPB;
    if (w <= gN - g0) {
        int g  = g0 + w;
        int lo = g * GROUPB;     if (lo < rbase)         lo = rbase;
        int hi = g * GROUPB + GROUPB; if (hi > rbase + RBINS) hi = rbase + RBINS;
        float p = 0.f;
        for (int i = lo - rbase + lane; i < hi - rbase; i += 64)
            p += __half2float(__float2half(s_all[i]));
        #pragma unroll
        for (int off = 32; off > 0; off >>= 1) p += __shfl_down(p, off, 64);
        if (lane == 0) atomicAdd(&gsum[g], p);
    }
}

// ============ k_final: fold slices + scan + Efron loss; last block finalizes ============
__global__ __launch_bounds__(1024) void k_final(
        const char* __restrict__ slices, const float* __restrict__ gsum,
        const float* __restrict__ lrp, const int* __restrict__ np,
        double* scal, int* done, float* __restrict__ out) {
    __shared__ float wtot[16];
    __shared__ float red_f[16];
    __shared__ int   red_i[16];
    __shared__ float sh_base;
    __shared__ int   sh_last;
    const int bid = blockIdx.x, tid = threadIdx.x;
    const int w = tid >> 6, lane = tid & 63;
    const int b = bid * GROUPB + tid;              // bin, valid if tid < GROUPB

    // fold NSL slices
    float a = 0.f, d = 0.f; int c = 0;
    if (tid < GROUPB) {
        for (int s = 0; s < NSL; ++s) {
            const char* sb = slices + (size_t)s * PER_SLICE;
            unsigned ab = ((const unsigned*)sb)[b];
            a += __half2float(__ushort_as_half((unsigned short)(ab & 0xFFFFu)));
            d += __half2float(__ushort_as_half((unsigned short)(ab >> 16)));
            c += ((const unsigned char*)(sb + 200000))[b];
        }
    }

    // prefix base from gsum (NFB=50 entries, wave 0)
    if (w == 0) {
        float gg = (lane < bid) ? gsum[lane] : 0.f;
        #pragma unroll
        for (int off = 32; off > 0; off >>= 1) gg += __shfl_down(gg, off, 64);
        if (lane == 0) sh_base = gg;
    }

    // in-block exclusive scan of a
    float x = a;
    #pragma unroll
    for (int off = 1; off < 64; off <<= 1) {
        float y = __shfl_up(x, off, 64);
        if (lane >= off) x += y;
    }
    if (lane == 63) wtot[w] = x;
    __syncthreads();
    float wb = 0.f;
    for (int i = 0; i < w; ++i) wb += wtot[i];
    float prefix = sh_base + wb + (x - a);         // risk over times strictly < t

    // Efron per-bin loss
    float acc = 0.f;
    if (tid < GROUPB && c > 0) {
        float D  = d;
        float nf = (float)c;
        float P  = D + (a - D) * (nf / (nf + 1.f));   // E[partial risk]
        float R  = prefix + P;
        for (int j = 0; j < c; ++j) {
            float arg = R - ((float)j / nf) * D + EPSF;
            acc += __logf(arg);
        }
    }
    #pragma unroll
    for (int off = 32; off > 0; off >>= 1) acc += __shfl_down(acc, off, 64);
    __syncthreads();
    if (lane == 0) red_f[w] = acc;
    __syncthreads();
    if (tid == 0) {
        float s = 0.f;
        #pragma unroll
        for (int i = 0; i < 16; ++i) s += red_f[i];
        atomicAdd(&scal[1], (double)s);
        __threadfence();
        int ticket = atomicAdd(done, 1);
        sh_last = (ticket == NFB - 1) ? 1 : 0;
    }
    __syncthreads();

    // last block finalizes: fold per-part-block scalars, write output
    if (sh_last) {
        float pl = (tid < NPB) ? lrp[tid] : 0.f;
        int   pn = (tid < NPB) ? np[tid]  : 0;
        #pragma unroll
        for (int off = 32; off > 0; off >>= 1) {
            pl += __shfl_down(pl, off, 64);
            pn += __shfl_down(pn, off, 64);
        }
        if (lane == 0) { red_f[w] = pl; red_i[w] = pn; }
        __syncthreads();
        if (tid == 0) {
            float s = 0.f; int n = 0;
            #pragma unroll
            for (int i = 0; i < 16; ++i) { s += red_f[i]; n += red_i[i]; }
            double logsum = atomicAdd(&scal[1], 0.0);   // coherent read of final sum
            out[0] = (n > 0) ? (float)((logsum - (double)s) / (double)n) : 0.f;
        }
    }
}

extern "C" void kernel_launch(void* const* d_in, const int* in_sizes, int n_in,
                              void* d_out, int out_size, void* d_ws, size_t ws_size,
                              hipStream_t stream) {
    const float* lr = (const float*)d_in[0];
    const int*   tm = (const int*)d_in[1];
    const int*   ev = (const int*)d_in[2];
    int N = in_sizes[0];

    char*     ws    = (char*)d_ws;
    double*   scal  = (double*)(ws + OFF_SCAL);
    int*      done  = (int*)(ws + OFF_DONE);
    float*    gsum  = (float*)(ws + OFF_GSUM);
    float*    lrp   = (float*)(ws + OFF_LRP);
    int*      np    = (int*)(ws + OFF_NP);
    unsigned* cnts  = (unsigned*)(ws + OFF_CNTS);
    unsigned* part  = (unsigned*)(ws + OFF_PART);

    // wave chunk, multiple of 256 elems
    int WCH = (int)((((long long)N + (NPB * NWV) - 1) / (NPB * NWV) + 255) / 256) * 256;
    size_t part_bytes = (size_t)NPB * NWV * 4 * WCH * 4;
    char* slices = ws + OFF_PART + part_bytes;   // NSL * PER_SLICE = 8.2 MB

    k_part<<<NPB, 1024, 0, stream>>>(lr, tm, ev, N, WCH, part, cnts, lrp, np,
                                     gsum, scal, done);
    k_pass<<<NR * NSL, 1024, 0, stream>>>(part, cnts, WCH, slices, gsum);
    k_final<<<NFB, 1024, 0, stream>>>(slices, gsum, lrp, np, scal, done,
                                      (float*)d_out);
}

// Round 10
// 93.837 us; speedup vs baseline: 1.1684x; 1.1684x over previous
//
#include <hip/hip_runtime.h>
#include <hip/hip_fp16.h>
#include <math.h>

#define TBINS   50000
#define NR      4
#define RBINS   12500          // TBINS / NR
#define EPSF    1e-7f
#define NPB     256            // partition blocks
#define NWV     16             // waves per partition block (1024 thr)
#define NSL     64             // pass slices (each covers NPB/NSL=4 part blocks)
#define NFB     50             // final blocks
#define GROUPB  1000           // bins per final block
#define PER_SLICE 256000       // u32 ab[TBINS] (200000) + u8 cnt[TBINS] (50000), padded

// ---- ws layout (byte offsets) ----
#define OFF_SCAL  0            // dbl[2]: [1]=log-sum accumulator
#define OFF_DONE  16           // int (k_final finalize ticket)
#define OFF_GSUM  64           // f32[NFB]
#define OFF_LRP   512          // f32[NPB]
#define OFF_NP    1536         // i32[NPB]
#define OFF_CNTS  4096         // u32[NPB*NWV*4]
#define OFF_PART  69632        // u32[NPB*NWV*4*WCH]

// ============ k_part: read raw once, pack+partition into per-(blk,wave,range) segments ============
__global__ __launch_bounds__(1024) void k_part(
        const float* __restrict__ lr, const int* __restrict__ tm,
        const int* __restrict__ ev, int N, int WCH,
        unsigned* __restrict__ part, unsigned* __restrict__ cnts,
        float* __restrict__ lrp, int* __restrict__ np,
        float* __restrict__ gsum, double* __restrict__ scal,
        int* __restrict__ done) {
    __shared__ float red_f[16];
    __shared__ int   red_i[16];
    const int b = blockIdx.x, tid = threadIdx.x;
    const int w = tid >> 6, lane = tid & 63;
    const unsigned long long lmask = (1ULL << lane) - 1ULL;

    // re-init cross-call state (replay-deterministic)
    if (b == 0) {
        if (tid < NFB) gsum[tid] = 0.f;
        if (tid == NFB)     scal[1] = 0.0;
        if (tid == NFB + 1) *done   = 0;
    }

    const int base0 = (b * NWV + w) * WCH;
    const unsigned seg0 = (unsigned)(b * NWV + w) * 4u;
    unsigned wc0 = 0, wc1 = 0, wc2 = 0, wc3 = 0;
    float l_lr = 0.f; int l_n = 0;

#define PART1(L, T, E, VALID) {                                           \
        float r_ = __expf(L);                                             \
        unsigned hb_ = (unsigned)__half_as_ushort(__float2half(r_));      \
        bool ve_ = (VALID) && ((E) != 0);                                 \
        if (ve_) { hb_ |= 0x8000u; l_lr += (L); l_n++; }                  \
        unsigned P_  = ((unsigned)(T) << 16) | hb_;                       \
        unsigned rg_ = ((unsigned)(T)) / 12500u;                          \
        { unsigned long long m_ = __ballot((VALID) && rg_ == 0u);         \
          if ((VALID) && rg_ == 0u)                                       \
              part[(size_t)(seg0 + 0u) * WCH + wc0 + (unsigned)__popcll(m_ & lmask)] = P_; \
          wc0 += (unsigned)__popcll(m_); }                                \
        { unsigned long long m_ = __ballot((VALID) && rg_ == 1u);         \
          if ((VALID) && rg_ == 1u)                                       \
              part[(size_t)(seg0 + 1u) * WCH + wc1 + (unsigned)__popcll(m_ & lmask)] = P_; \
          wc1 += (unsigned)__popcll(m_); }                                \
        { unsigned long long m_ = __ballot((VALID) && rg_ == 2u);         \
          if ((VALID) && rg_ == 2u)                                       \
              part[(size_t)(seg0 + 2u) * WCH + wc2 + (unsigned)__popcll(m_ & lmask)] = P_; \
          wc2 += (unsigned)__popcll(m_); }                                \
        { unsigned long long m_ = __ballot((VALID) && rg_ == 3u);         \
          if ((VALID) && rg_ == 3u)                                       \
              part[(size_t)(seg0 + 3u) * WCH + wc3 + (unsigned)__popcll(m_ & lmask)] = P_; \
          wc3 += (unsigned)__popcll(m_); }                                \
    }

    for (int it = 0; it < WCH; it += 256) {
        int idx = base0 + it + lane * 4;
        float4 l4 = {0.f, 0.f, 0.f, 0.f};
        int4   t4 = {0, 0, 0, 0};
        int4   e4 = {0, 0, 0, 0};
        if (idx + 3 < N) {
            l4 = *(const float4*)(lr + idx);
            t4 = *(const int4*)(tm + idx);
            e4 = *(const int4*)(ev + idx);
        } else if (idx < N) {
            float* lp = (float*)&l4; int* tp = (int*)&t4; int* ep = (int*)&e4;
            for (int k = 0; k < 4 && idx + k < N; ++k) {
                lp[k] = lr[idx + k]; tp[k] = tm[idx + k]; ep[k] = ev[idx + k];
            }
        }
        PART1(l4.x, t4.x, e4.x, (idx + 0) < N)
        PART1(l4.y, t4.y, e4.y, (idx + 1) < N)
        PART1(l4.z, t4.z, e4.z, (idx + 2) < N)
        PART1(l4.w, t4.w, e4.w, (idx + 3) < N)
    }

    if (lane == 0) {
        unsigned* c = cnts + seg0;
        c[0] = wc0; c[1] = wc1; c[2] = wc2; c[3] = wc3;
    }

    #pragma unroll
    for (int off = 32; off > 0; off >>= 1) {
        l_lr += __shfl_down(l_lr, off, 64);
        l_n  += __shfl_down(l_n,  off, 64);
    }
    if (lane == 0) { red_f[w] = l_lr; red_i[w] = l_n; }
    __syncthreads();
    if (tid == 0) {
        float s = 0.f; int c = 0;
        #pragma unroll
        for (int i = 0; i < NWV; ++i) { s += red_f[i]; c += red_i[i]; }
        lrp[b] = s; np[b] = c;
    }
}

// ============ k_pass: single-visit LDS histogram per (range, slice); also gsum partials ============
__global__ __launch_bounds__(1024) void k_pass(
        const unsigned* __restrict__ part, const unsigned* __restrict__ cnts,
        int WCH, char* __restrict__ slices, float* __restrict__ gsum) {
    __shared__ float    s_all[RBINS];
    __shared__ unsigned s_evcnt[RBINS];   // (count<<28) | fixed12.16(sum exp over events)
    const int bid = blockIdx.x;
    const int r = bid & 3, s = bid >> 2;
    const int rbase = r * RBINS;
    const int tid = threadIdx.x, w = tid >> 6, lane = tid & 63;

    for (int i = tid; i < RBINS; i += 1024) { s_all[i] = 0.f; s_evcnt[i] = 0u; }
    __syncthreads();

#define PROC1(P) {                                                        \
        unsigned rel_ = ((P) >> 16) - (unsigned)rbase;                    \
        if (rel_ < (unsigned)RBINS) {                                     \
            float r_ = __half2float(__ushort_as_half((unsigned short)((P) & 0x7FFFu))); \
            atomicAdd(&s_all[rel_], r_);                                  \
            if ((P) & 0x8000u) {                                          \
                unsigned enc_ = (1u << 28) + (unsigned)(r_ * 65536.0f + 0.5f); \
                atomicAdd(&s_evcnt[rel_], enc_);                          \
            }                                                             \
        } }

    // 64 segments feed this block: part-blocks [4s,4s+4) x 16 waves; wave w takes 4.
    // Vectorized gather: 4 elems/lane/iter (one round covers a typical 256-elem segment).
    for (int sl = w; sl < 4 * NWV; sl += NWV) {
        int pb = 4 * s + (sl >> 4);
        int pw = sl & 15;
        unsigned seg = (unsigned)(pb * NWV + pw) * 4u + (unsigned)r;
        unsigned cnt = cnts[seg];
        const unsigned* sp = part + (size_t)seg * WCH;
        for (unsigned i = (unsigned)lane * 4u; i + 3u < cnt; i += 256u) {
            uint4 P4 = *(const uint4*)(sp + i);
            PROC1(P4.x) PROC1(P4.y) PROC1(P4.z) PROC1(P4.w)
        }
        for (unsigned i = (cnt & ~3u) + (unsigned)lane; i < cnt; i += 64u) {
            unsigned P = sp[i];
            PROC1(P)
        }
    }
    __syncthreads();

    // flush: f16(all)|f16(ev) + u8 count
    char* sb = slices + (size_t)s * PER_SLICE;
    unsigned*      wab = (unsigned*)sb;
    unsigned char* wcq = (unsigned char*)(sb + 200000);
    for (int i = tid; i < RBINS; i += 1024) {
        float a = s_all[i];
        unsigned ec = s_evcnt[i];
        float e = (float)(ec & 0x0FFFFFFFu) * (1.0f / 65536.0f);
        wab[rbase + i] = (unsigned)__half_as_ushort(__float2half(a))
                       | ((unsigned)__half_as_ushort(__float2half(e)) << 16);
        wcq[rbase + i] = (unsigned char)(ec >> 28);
    }

    // group partials for the prefix base, from f16-round-tripped values (consistency)
    int g0 = rbase / GROUPB;
    int gN = (rbase + RBINS - 1) / GROUPB;
    if (w <= gN - g0) {
        int g  = g0 + w;
        int lo = g * GROUPB;          if (lo < rbase)         lo = rbase;
        int hi = g * GROUPB + GROUPB; if (hi > rbase + RBINS) hi = rbase + RBINS;
        float p = 0.f;
        for (int i = lo - rbase + lane; i < hi - rbase; i += 64)
            p += __half2float(__float2half(s_all[i]));
        #pragma unroll
        for (int off = 32; off > 0; off >>= 1) p += __shfl_down(p, off, 64);
        if (lane == 0) atomicAdd(&gsum[g], p);
    }
}

// ============ k_final: fold slices + scan + Efron loss; last block finalizes ============
__global__ __launch_bounds__(1024) void k_final(
        const char* __restrict__ slices, const float* __restrict__ gsum,
        const float* __restrict__ lrp, const int* __restrict__ np,
        double* scal, int* done, float* __restrict__ out) {
    __shared__ float wtot[16];
    __shared__ float red_f[16];
    __shared__ int   red_i[16];
    __shared__ float sh_base;
    __shared__ int   sh_last;
    const int bid = blockIdx.x, tid = threadIdx.x;
    const int w = tid >> 6, lane = tid & 63;
    const int b = bid * GROUPB + tid;              // bin, valid if tid < GROUPB

    // fold NSL slices
    float a = 0.f, d = 0.f; int c = 0;
    if (tid < GROUPB) {
        for (int s = 0; s < NSL; ++s) {
            const char* sb = slices + (size_t)s * PER_SLICE;
            unsigned ab = ((const unsigned*)sb)[b];
            a += __half2float(__ushort_as_half((unsigned short)(ab & 0xFFFFu)));
            d += __half2float(__ushort_as_half((unsigned short)(ab >> 16)));
            c += ((const unsigned char*)(sb + 200000))[b];
        }
    }

    // prefix base from gsum (NFB=50 entries, wave 0)
    if (w == 0) {
        float gg = (lane < bid) ? gsum[lane] : 0.f;
        #pragma unroll
        for (int off = 32; off > 0; off >>= 1) gg += __shfl_down(gg, off, 64);
        if (lane == 0) sh_base = gg;
    }

    // in-block exclusive scan of a
    float x = a;
    #pragma unroll
    for (int off = 1; off < 64; off <<= 1) {
        float y = __shfl_up(x, off, 64);
        if (lane >= off) x += y;
    }
    if (lane == 63) wtot[w] = x;
    __syncthreads();
    float wb = 0.f;
    for (int i = 0; i < w; ++i) wb += wtot[i];
    float prefix = sh_base + wb + (x - a);         // risk over times strictly < t

    // Efron per-bin loss
    float acc = 0.f;
    if (tid < GROUPB && c > 0) {
        float D  = d;
        float nf = (float)c;
        float P  = D + (a - D) * (nf / (nf + 1.f));   // E[partial risk]
        float R  = prefix + P;
        for (int j = 0; j < c; ++j) {
            float arg = R - ((float)j / nf) * D + EPSF;
            acc += __logf(arg);
        }
    }
    #pragma unroll
    for (int off = 32; off > 0; off >>= 1) acc += __shfl_down(acc, off, 64);
    __syncthreads();
    if (lane == 0) red_f[w] = acc;
    __syncthreads();
    if (tid == 0) {
        float s = 0.f;
        #pragma unroll
        for (int i = 0; i < 16; ++i) s += red_f[i];
        atomicAdd(&scal[1], (double)s);
        __threadfence();
        int ticket = atomicAdd(done, 1);
        sh_last = (ticket == NFB - 1) ? 1 : 0;
    }
    __syncthreads();

    // last block finalizes: fold per-part-block scalars, write output
    if (sh_last) {
        float pl = (tid < NPB) ? lrp[tid] : 0.f;
        int   pn = (tid < NPB) ? np[tid]  : 0;
        #pragma unroll
        for (int off = 32; off > 0; off >>= 1) {
            pl += __shfl_down(pl, off, 64);
            pn += __shfl_down(pn, off, 64);
        }
        if (lane == 0) { red_f[w] = pl; red_i[w] = pn; }
        __syncthreads();
        if (tid == 0) {
            float s = 0.f; int n = 0;
            #pragma unroll
            for (int i = 0; i < 16; ++i) { s += red_f[i]; n += red_i[i]; }
            double logsum = atomicAdd(&scal[1], 0.0);   // coherent read of final sum
            out[0] = (n > 0) ? (float)((logsum - (double)s) / (double)n) : 0.f;
        }
    }
}

extern "C" void kernel_launch(void* const* d_in, const int* in_sizes, int n_in,
                              void* d_out, int out_size, void* d_ws, size_t ws_size,
                              hipStream_t stream) {
    const float* lr = (const float*)d_in[0];
    const int*   tm = (const int*)d_in[1];
    const int*   ev = (const int*)d_in[2];
    int N = in_sizes[0];

    char*     ws    = (char*)d_ws;
    double*   scal  = (double*)(ws + OFF_SCAL);
    int*      done  = (int*)(ws + OFF_DONE);
    float*    gsum  = (float*)(ws + OFF_GSUM);
    float*    lrp   = (float*)(ws + OFF_LRP);
    int*      np    = (int*)(ws + OFF_NP);
    unsigned* cnts  = (unsigned*)(ws + OFF_CNTS);
    unsigned* part  = (unsigned*)(ws + OFF_PART);

    // wave chunk, multiple of 256 elems
    int WCH = (int)((((long long)N + (NPB * NWV) - 1) / (NPB * NWV) + 255) / 256) * 256;
    size_t part_bytes = (size_t)NPB * NWV * 4 * WCH * 4;
    char* slices = ws + OFF_PART + part_bytes;   // NSL * PER_SLICE = 16.4 MB

    k_part<<<NPB, 1024, 0, stream>>>(lr, tm, ev, N, WCH, part, cnts, lrp, np,
                                     gsum, scal, done);
    k_pass<<<NR * NSL, 1024, 0, stream>>>(part, cnts, WCH, slices, gsum);
    k_final<<<NFB, 1024, 0, stream>>>(slices, gsum, lrp, np, scal, done,
                                      (float*)d_out);
}

// Round 11
// 90.387 us; speedup vs baseline: 1.2130x; 1.0382x over previous
//
#include <hip/hip_runtime.h>
#include <hip/hip_fp16.h>
#include <math.h>

#define TBINS   50000
#define NR      4
#define RBINS   12500          // TBINS / NR
#define EPSF    1e-7f
#define NPB     256            // partition blocks
#define NWV     16             // waves per partition block (1024 thr)
#define NSL     64             // pass slices (each covers NPB/NSL=4 part blocks)
#define NFB     50             // final blocks
#define GROUPB  1000           // bins per final block
#define PER_SLICE 256000       // u32 ab[TBINS] (200000) + u8 cnt[TBINS] (50000), padded

// ---- ws layout (byte offsets) ----
#define OFF_SCAL  0            // dbl[2]: [1]=log-sum accumulator
#define OFF_DONE  16           // int (k_final finalize ticket)
#define OFF_GSUM  64           // f32[NFB]
#define OFF_LRP   512          // f32[NPB]
#define OFF_NP    1536         // i32[NPB]
#define OFF_CNTS  4096         // u32[NPB*NWV*4]
#define OFF_PART  69632        // u32[NPB*NWV*4*WCH]

// ============ k_part: read raw once, pack+partition into per-(blk,wave,range) segments ============
__global__ __launch_bounds__(1024) void k_part(
        const float* __restrict__ lr, const int* __restrict__ tm,
        const int* __restrict__ ev, int N, int WCH,
        unsigned* __restrict__ part, unsigned* __restrict__ cnts,
        float* __restrict__ lrp, int* __restrict__ np,
        float* __restrict__ gsum, double* __restrict__ scal,
        int* __restrict__ done) {
    __shared__ float red_f[16];
    __shared__ int   red_i[16];
    const int b = blockIdx.x, tid = threadIdx.x;
    const int w = tid >> 6, lane = tid & 63;
    const unsigned long long lmask = (1ULL << lane) - 1ULL;

    // re-init cross-call state (replay-deterministic)
    if (b == 0) {
        if (tid < NFB) gsum[tid] = 0.f;
        if (tid == NFB)     scal[1] = 0.0;
        if (tid == NFB + 1) *done   = 0;
    }

    const int base0 = (b * NWV + w) * WCH;
    const unsigned seg0 = (unsigned)(b * NWV + w) * 4u;
    unsigned wc0 = 0, wc1 = 0, wc2 = 0, wc3 = 0;
    float l_lr = 0.f; int l_n = 0;

#define PART1(L, T, E, VALID) {                                           \
        float r_ = __expf(L);                                             \
        unsigned hb_ = (unsigned)__half_as_ushort(__float2half(r_));      \
        bool ve_ = (VALID) && ((E) != 0);                                 \
        if (ve_) { hb_ |= 0x8000u; l_lr += (L); l_n++; }                  \
        unsigned P_  = ((unsigned)(T) << 16) | hb_;                       \
        unsigned rg_ = ((unsigned)(T)) / 12500u;                          \
        { unsigned long long m_ = __ballot((VALID) && rg_ == 0u);         \
          if ((VALID) && rg_ == 0u)                                       \
              part[(size_t)(seg0 + 0u) * WCH + wc0 + (unsigned)__popcll(m_ & lmask)] = P_; \
          wc0 += (unsigned)__popcll(m_); }                                \
        { unsigned long long m_ = __ballot((VALID) && rg_ == 1u);         \
          if ((VALID) && rg_ == 1u)                                       \
              part[(size_t)(seg0 + 1u) * WCH + wc1 + (unsigned)__popcll(m_ & lmask)] = P_; \
          wc1 += (unsigned)__popcll(m_); }                                \
        { unsigned long long m_ = __ballot((VALID) && rg_ == 2u);         \
          if ((VALID) && rg_ == 2u)                                       \
              part[(size_t)(seg0 + 2u) * WCH + wc2 + (unsigned)__popcll(m_ & lmask)] = P_; \
          wc2 += (unsigned)__popcll(m_); }                                \
        { unsigned long long m_ = __ballot((VALID) && rg_ == 3u);         \
          if ((VALID) && rg_ == 3u)                                       \
              part[(size_t)(seg0 + 3u) * WCH + wc3 + (unsigned)__popcll(m_ & lmask)] = P_; \
          wc3 += (unsigned)__popcll(m_); }                                \
    }

    for (int it = 0; it < WCH; it += 256) {
        int idx = base0 + it + lane * 4;
        float4 l4 = {0.f, 0.f, 0.f, 0.f};
        int4   t4 = {0, 0, 0, 0};
        int4   e4 = {0, 0, 0, 0};
        if (idx + 3 < N) {
            l4 = *(const float4*)(lr + idx);
            t4 = *(const int4*)(tm + idx);
            e4 = *(const int4*)(ev + idx);
        } else if (idx < N) {
            float* lp = (float*)&l4; int* tp = (int*)&t4; int* ep = (int*)&e4;
            for (int k = 0; k < 4 && idx + k < N; ++k) {
                lp[k] = lr[idx + k]; tp[k] = tm[idx + k]; ep[k] = ev[idx + k];
            }
        }
        PART1(l4.x, t4.x, e4.x, (idx + 0) < N)
        PART1(l4.y, t4.y, e4.y, (idx + 1) < N)
        PART1(l4.z, t4.z, e4.z, (idx + 2) < N)
        PART1(l4.w, t4.w, e4.w, (idx + 3) < N)
    }

    if (lane == 0) {
        unsigned* c = cnts + seg0;
        c[0] = wc0; c[1] = wc1; c[2] = wc2; c[3] = wc3;
    }

    #pragma unroll
    for (int off = 32; off > 0; off >>= 1) {
        l_lr += __shfl_down(l_lr, off, 64);
        l_n  += __shfl_down(l_n,  off, 64);
    }
    if (lane == 0) { red_f[w] = l_lr; red_i[w] = l_n; }
    __syncthreads();
    if (tid == 0) {
        float s = 0.f; int c = 0;
        #pragma unroll
        for (int i = 0; i < NWV; ++i) { s += red_f[i]; c += red_i[i]; }
        lrp[b] = s; np[b] = c;
    }
}

// ============ k_pass: single-visit LDS histogram per (range, slice); also gsum partials ============
__global__ __launch_bounds__(1024) void k_pass(
        const unsigned* __restrict__ part, const unsigned* __restrict__ cnts,
        int WCH, char* __restrict__ slices, float* __restrict__ gsum) {
    __shared__ float    s_all[RBINS];
    __shared__ unsigned s_evcnt[RBINS];   // (count<<28) | fixed12.16(sum exp over events)
    const int bid = blockIdx.x;
    const int r = bid & 3, s = bid >> 2;
    const int rbase = r * RBINS;
    const int tid = threadIdx.x, w = tid >> 6, lane = tid & 63;

    for (int i = tid; i < RBINS; i += 1024) { s_all[i] = 0.f; s_evcnt[i] = 0u; }
    __syncthreads();

#define PROC1(P) {                                                        \
        unsigned rel_ = ((P) >> 16) - (unsigned)rbase;                    \
        if (rel_ < (unsigned)RBINS) {                                     \
            float r_ = __half2float(__ushort_as_half((unsigned short)((P) & 0x7FFFu))); \
            atomicAdd(&s_all[rel_], r_);                                  \
            if ((P) & 0x8000u) {                                          \
                unsigned enc_ = (1u << 28) + (unsigned)(r_ * 65536.0f + 0.5f); \
                atomicAdd(&s_evcnt[rel_], enc_);                          \
            }                                                             \
        } }

    // 64 segments feed this block: part-blocks [4s,4s+4) x 16 waves; wave w takes 4.
    // Hoist the 4 counts (independent loads), then scalar gather: each inner
    // loop's iterations are independent loads the compiler can keep in flight
    // (the uint4 variant had ONE load in flight per segment -> latency-bound, R10).
    {
        unsigned segs[4], cnt4[4];
        #pragma unroll
        for (int q = 0; q < 4; ++q) {
            int pb = 4 * s + q;
            segs[q] = (unsigned)(pb * NWV + w) * 4u + (unsigned)r;
        }
        #pragma unroll
        for (int q = 0; q < 4; ++q) cnt4[q] = cnts[segs[q]];
        #pragma unroll
        for (int q = 0; q < 4; ++q) {
            const unsigned* sp = part + (size_t)segs[q] * WCH;
            unsigned cnt = cnt4[q];
            for (unsigned i = (unsigned)lane; i < cnt; i += 64u) {
                unsigned P = sp[i];
                PROC1(P)
            }
        }
    }
    __syncthreads();

    // flush: f16(all)|f16(ev) + u8 count
    char* sb = slices + (size_t)s * PER_SLICE;
    unsigned*      wab = (unsigned*)sb;
    unsigned char* wcq = (unsigned char*)(sb + 200000);
    for (int i = tid; i < RBINS; i += 1024) {
        float a = s_all[i];
        unsigned ec = s_evcnt[i];
        float e = (float)(ec & 0x0FFFFFFFu) * (1.0f / 65536.0f);
        wab[rbase + i] = (unsigned)__half_as_ushort(__float2half(a))
                       | ((unsigned)__half_as_ushort(__float2half(e)) << 16);
        wcq[rbase + i] = (unsigned char)(ec >> 28);
    }

    // group partials for the prefix base, from f16-round-tripped values (consistency)
    int g0 = rbase / GROUPB;
    int gN = (rbase + RBINS - 1) / GROUPB;
    if (w <= gN - g0) {
        int g  = g0 + w;
        int lo = g * GROUPB;          if (lo < rbase)         lo = rbase;
        int hi = g * GROUPB + GROUPB; if (hi > rbase + RBINS) hi = rbase + RBINS;
        float p = 0.f;
        for (int i = lo - rbase + lane; i < hi - rbase; i += 64)
            p += __half2float(__float2half(s_all[i]));
        #pragma unroll
        for (int off = 32; off > 0; off >>= 1) p += __shfl_down(p, off, 64);
        if (lane == 0) atomicAdd(&gsum[g], p);
    }
}

// ============ k_final: fold slices + scan + Efron loss; last block finalizes ============
__global__ __launch_bounds__(1024) void k_final(
        const char* __restrict__ slices, const float* __restrict__ gsum,
        const float* __restrict__ lrp, const int* __restrict__ np,
        double* scal, int* done, float* __restrict__ out) {
    __shared__ float wtot[16];
    __shared__ float red_f[16];
    __shared__ int   red_i[16];
    __shared__ float sh_base;
    __shared__ int   sh_last;
    const int bid = blockIdx.x, tid = threadIdx.x;
    const int w = tid >> 6, lane = tid & 63;
    const int b = bid * GROUPB + tid;              // bin, valid if tid < GROUPB

    // fold NSL slices
    float a = 0.f, d = 0.f; int c = 0;
    if (tid < GROUPB) {
        for (int s = 0; s < NSL; ++s) {
            const char* sb = slices + (size_t)s * PER_SLICE;
            unsigned ab = ((const unsigned*)sb)[b];
            a += __half2float(__ushort_as_half((unsigned short)(ab & 0xFFFFu)));
            d += __half2float(__ushort_as_half((unsigned short)(ab >> 16)));
            c += ((const unsigned char*)(sb + 200000))[b];
        }
    }

    // prefix base from gsum (NFB=50 entries, wave 0)
    if (w == 0) {
        float gg = (lane < bid) ? gsum[lane] : 0.f;
        #pragma unroll
        for (int off = 32; off > 0; off >>= 1) gg += __shfl_down(gg, off, 64);
        if (lane == 0) sh_base = gg;
    }

    // in-block exclusive scan of a
    float x = a;
    #pragma unroll
    for (int off = 1; off < 64; off <<= 1) {
        float y = __shfl_up(x, off, 64);
        if (lane >= off) x += y;
    }
    if (lane == 63) wtot[w] = x;
    __syncthreads();
    float wb = 0.f;
    for (int i = 0; i < w; ++i) wb += wtot[i];
    float prefix = sh_base + wb + (x - a);         // risk over times strictly < t

    // Efron per-bin loss
    float acc = 0.f;
    if (tid < GROUPB && c > 0) {
        float D  = d;
        float nf = (float)c;
        float P  = D + (a - D) * (nf / (nf + 1.f));   // E[partial risk]
        float R  = prefix + P;
        for (int j = 0; j < c; ++j) {
            float arg = R - ((float)j / nf) * D + EPSF;
            acc += __logf(arg);
        }
    }
    #pragma unroll
    for (int off = 32; off > 0; off >>= 1) acc += __shfl_down(acc, off, 64);
    __syncthreads();
    if (lane == 0) red_f[w] = acc;
    __syncthreads();
    if (tid == 0) {
        float s = 0.f;
        #pragma unroll
        for (int i = 0; i < 16; ++i) s += red_f[i];
        atomicAdd(&scal[1], (double)s);
        __threadfence();
        int ticket = atomicAdd(done, 1);
        sh_last = (ticket == NFB - 1) ? 1 : 0;
    }
    __syncthreads();

    // last block finalizes: fold per-part-block scalars, write output
    if (sh_last) {
        float pl = (tid < NPB) ? lrp[tid] : 0.f;
        int   pn = (tid < NPB) ? np[tid]  : 0;
        #pragma unroll
        for (int off = 32; off > 0; off >>= 1) {
            pl += __shfl_down(pl, off, 64);
            pn += __shfl_down(pn, off, 64);
        }
        if (lane == 0) { red_f[w] = pl; red_i[w] = pn; }
        __syncthreads();
        if (tid == 0) {
            float s = 0.f; int n = 0;
            #pragma unroll
            for (int i = 0; i < 16; ++i) { s += red_f[i]; n += red_i[i]; }
            double logsum = atomicAdd(&scal[1], 0.0);   // coherent read of final sum
            out[0] = (n > 0) ? (float)((logsum - (double)s) / (double)n) : 0.f;
        }
    }
}

extern "C" void kernel_launch(void* const* d_in, const int* in_sizes, int n_in,
                              void* d_out, int out_size, void* d_ws, size_t ws_size,
                              hipStream_t stream) {
    const float* lr = (const float*)d_in[0];
    const int*   tm = (const int*)d_in[1];
    const int*   ev = (const int*)d_in[2];
    int N = in_sizes[0];

    char*     ws    = (char*)d_ws;
    double*   scal  = (double*)(ws + OFF_SCAL);
    int*      done  = (int*)(ws + OFF_DONE);
    float*    gsum  = (float*)(ws + OFF_GSUM);
    float*    lrp   = (float*)(ws + OFF_LRP);
    int*      np    = (int*)(ws + OFF_NP);
    unsigned* cnts  = (unsigned*)(ws + OFF_CNTS);
    unsigned* part  = (unsigned*)(ws + OFF_PART);

    // wave chunk, multiple of 256 elems
    int WCH = (int)((((long long)N + (NPB * NWV) - 1) / (NPB * NWV) + 255) / 256) * 256;
    size_t part_bytes = (size_t)NPB * NWV * 4 * WCH * 4;
    char* slices = ws + OFF_PART + part_bytes;   // NSL * PER_SLICE = 16.4 MB

    k_part<<<NPB, 1024, 0, stream>>>(lr, tm, ev, N, WCH, part, cnts, lrp, np,
                                     gsum, scal, done);
    k_pass<<<NR * NSL, 1024, 0, stream>>>(part, cnts, WCH, slices, gsum);
    k_final<<<NFB, 1024, 0, stream>>>(slices, gsum, lrp, np, scal, done,
                                      (float*)d_out);
}

// Round 12
// 85.767 us; speedup vs baseline: 1.2783x; 1.0539x over previous
//
#include <hip/hip_runtime.h>
#include <hip/hip_fp16.h>
#include <math.h>

#define TBINS   50000
#define NR      8
#define RBINS   6250           // TBINS / NR
#define EPSF    1e-7f
#define NPB     256            // partition blocks
#define NWV     16             // waves per partition block (1024 thr)
#define NSL     64             // pass slices (each covers 64 wave-groups)
#define NFB     50             // final blocks
#define GROUPB  1000           // bins per final block
#define PER_SLICE 256000       // u32 ab[TBINS] (200000) + u8 cnt[TBINS] (50000), padded

// ---- ws layout (byte offsets) ----
#define OFF_SCAL  0            // dbl[2]: [1]=log-sum accumulator
#define OFF_DONE  16           // int (k_final finalize ticket)
#define OFF_GSUM  64           // f32[NFB]
#define OFF_LRP   512          // f32[NPB]
#define OFF_NP    1536         // i32[NPB]
#define OFF_CNTS  4096         // u32[NPB*NWV*NR] = 128 KB
#define OFF_PART  139264       // u32[NPB*NWV*NR*CAP]

// ============ k_part: read raw once, pack+partition into per-(wave,range) segments ============
__global__ __launch_bounds__(1024) void k_part(
        const float* __restrict__ lr, const int* __restrict__ tm,
        const int* __restrict__ ev, int N, int WCH, int CAP,
        unsigned* __restrict__ part, unsigned* __restrict__ cnts,
        float* __restrict__ lrp, int* __restrict__ np,
        float* __restrict__ gsum, double* __restrict__ scal,
        int* __restrict__ done) {
    __shared__ float red_f[16];
    __shared__ int   red_i[16];
    const int b = blockIdx.x, tid = threadIdx.x;
    const int w = tid >> 6, lane = tid & 63;
    const unsigned long long lmask = (1ULL << lane) - 1ULL;

    // re-init cross-call state (replay-deterministic)
    if (b == 0) {
        if (tid < NFB) gsum[tid] = 0.f;
        if (tid == NFB)     scal[1] = 0.0;
        if (tid == NFB + 1) *done   = 0;
    }

    const int wg    = b * NWV + w;           // wave-group id [0, 4096)
    const int base0 = wg * WCH;
    const unsigned seg0 = (unsigned)wg * (unsigned)NR;
    unsigned wc[NR];
    #pragma unroll
    for (int r = 0; r < NR; ++r) wc[r] = 0u;
    float l_lr = 0.f; int l_n = 0;

#define PART1(L, T, E, VALID) {                                           \
        float r_ = __expf(L);                                             \
        unsigned hb_ = (unsigned)__half_as_ushort(__float2half(r_));      \
        bool ve_ = (VALID) && ((E) != 0);                                 \
        if (ve_) { hb_ |= 0x8000u; l_lr += (L); l_n++; }                  \
        unsigned P_  = ((unsigned)(T) << 16) | hb_;                       \
        unsigned rg_ = ((unsigned)(T)) / (unsigned)RBINS;                 \
        _Pragma("unroll")                                                 \
        for (int r = 0; r < NR; ++r) {                                    \
            bool hit_ = (VALID) && (rg_ == (unsigned)r);                  \
            unsigned long long m_ = __ballot(hit_);                       \
            if (hit_) {                                                   \
                unsigned pos_ = wc[r] + (unsigned)__popcll(m_ & lmask);   \
                if (pos_ < (unsigned)CAP)                                 \
                    part[(size_t)(seg0 + (unsigned)r) * (unsigned)CAP + pos_] = P_; \
            }                                                             \
            wc[r] += (unsigned)__popcll(m_);                              \
        } }

    for (int it = 0; it < WCH; it += 256) {
        int idx = base0 + it + lane * 4;
        float4 l4 = {0.f, 0.f, 0.f, 0.f};
        int4   t4 = {0, 0, 0, 0};
        int4   e4 = {0, 0, 0, 0};
        if (idx + 3 < N) {
            l4 = *(const float4*)(lr + idx);
            t4 = *(const int4*)(tm + idx);
            e4 = *(const int4*)(ev + idx);
        } else if (idx < N) {
            float* lp = (float*)&l4; int* tp = (int*)&t4; int* ep = (int*)&e4;
            for (int k = 0; k < 4 && idx + k < N; ++k) {
                lp[k] = lr[idx + k]; tp[k] = tm[idx + k]; ep[k] = ev[idx + k];
            }
        }
        PART1(l4.x, t4.x, e4.x, (idx + 0) < N)
        PART1(l4.y, t4.y, e4.y, (idx + 1) < N)
        PART1(l4.z, t4.z, e4.z, (idx + 2) < N)
        PART1(l4.w, t4.w, e4.w, (idx + 3) < N)
    }

    if (lane == 0) {
        #pragma unroll
        for (int r = 0; r < NR; ++r) cnts[seg0 + r] = wc[r];
    }

    #pragma unroll
    for (int off = 32; off > 0; off >>= 1) {
        l_lr += __shfl_down(l_lr, off, 64);
        l_n  += __shfl_down(l_n,  off, 64);
    }
    if (lane == 0) { red_f[w] = l_lr; red_i[w] = l_n; }
    __syncthreads();
    if (tid == 0) {
        float s = 0.f; int c = 0;
        #pragma unroll
        for (int i = 0; i < NWV; ++i) { s += red_f[i]; c += red_i[i]; }
        lrp[b] = s; np[b] = c;
    }
}

// ============ k_pass: single-visit LDS histogram per (range, slice); native u32 atomics only ============
__global__ __launch_bounds__(1024) void k_pass(
        const unsigned* __restrict__ part, const unsigned* __restrict__ cnts,
        int CAP, char* __restrict__ slices, float* __restrict__ gsum) {
    __shared__ unsigned s_all[RBINS];     // fixed-point 24.8 sum of exp
    __shared__ unsigned s_evcnt[RBINS];   // (count<<28) | fixed12.16(sum exp over events)
    const int bid = blockIdx.x;
    const int r = bid & 7, s = bid >> 3;
    const int rbase = r * RBINS;
    const int tid = threadIdx.x, w = tid >> 6, lane = tid & 63;

    for (int i = tid; i < RBINS; i += 1024) { s_all[i] = 0u; s_evcnt[i] = 0u; }
    __syncthreads();

#define PROC1(P) {                                                        \
        unsigned rel_ = ((P) >> 16) - (unsigned)rbase;                    \
        if (rel_ < (unsigned)RBINS) {                                     \
            float r_ = __half2float(__ushort_as_half((unsigned short)((P) & 0x7FFFu))); \
            atomicAdd(&s_all[rel_], (unsigned)(r_ * 256.0f + 0.5f));      \
            if ((P) & 0x8000u) {                                          \
                unsigned enc_ = (1u << 28) + (unsigned)(r_ * 65536.0f + 0.5f); \
                atomicAdd(&s_evcnt[rel_], enc_);                          \
            }                                                             \
        } }

    // 64 wave-groups feed this block; wave w takes 4 of them (one range-r segment each)
    {
        unsigned segs[4], cnt4[4];
        #pragma unroll
        for (int q = 0; q < 4; ++q) {
            int wg = s * 64 + w * 4 + q;
            segs[q] = (unsigned)wg * (unsigned)NR + (unsigned)r;
        }
        #pragma unroll
        for (int q = 0; q < 4; ++q) {
            unsigned c = cnts[segs[q]];
            cnt4[q] = (c > (unsigned)CAP) ? (unsigned)CAP : c;
        }
        #pragma unroll
        for (int q = 0; q < 4; ++q) {
            const unsigned* sp = part + (size_t)segs[q] * (unsigned)CAP;
            unsigned cnt = cnt4[q];
            for (unsigned i = (unsigned)lane; i < cnt; i += 64u) {
                unsigned P = sp[i];
                PROC1(P)
            }
        }
    }
    __syncthreads();

    // flush: f16(all)|f16(ev) + u8 count
    char* sb = slices + (size_t)s * PER_SLICE;
    unsigned*      wab = (unsigned*)sb;
    unsigned char* wcq = (unsigned char*)(sb + 200000);
    for (int i = tid; i < RBINS; i += 1024) {
        float a = (float)s_all[i] * (1.0f / 256.0f);
        unsigned ec = s_evcnt[i];
        float e = (float)(ec & 0x0FFFFFFFu) * (1.0f / 65536.0f);
        wab[rbase + i] = (unsigned)__half_as_ushort(__float2half(a))
                       | ((unsigned)__half_as_ushort(__float2half(e)) << 16);
        wcq[rbase + i] = (unsigned char)(ec >> 28);
    }

    // group partials for the prefix base, from f16-round-tripped values (consistency)
    int g0 = rbase / GROUPB;
    int gN = (rbase + RBINS - 1) / GROUPB;
    if (w <= gN - g0) {
        int g  = g0 + w;
        int lo = g * GROUPB;          if (lo < rbase)         lo = rbase;
        int hi = g * GROUPB + GROUPB; if (hi > rbase + RBINS) hi = rbase + RBINS;
        float p = 0.f;
        for (int i = lo - rbase + lane; i < hi - rbase; i += 64) {
            float a = (float)s_all[i] * (1.0f / 256.0f);
            p += __half2float(__float2half(a));
        }
        #pragma unroll
        for (int off = 32; off > 0; off >>= 1) p += __shfl_down(p, off, 64);
        if (lane == 0) atomicAdd(&gsum[g], p);
    }
}

// ============ k_final: fold slices + scan + Efron loss; last block finalizes ============
__global__ __launch_bounds__(1024) void k_final(
        const char* __restrict__ slices, const float* __restrict__ gsum,
        const float* __restrict__ lrp, const int* __restrict__ np,
        double* scal, int* done, float* __restrict__ out) {
    __shared__ float wtot[16];
    __shared__ float red_f[16];
    __shared__ int   red_i[16];
    __shared__ float sh_base;
    __shared__ int   sh_last;
    const int bid = blockIdx.x, tid = threadIdx.x;
    const int w = tid >> 6, lane = tid & 63;
    const int b = bid * GROUPB + tid;              // bin, valid if tid < GROUPB

    // fold NSL slices
    float a = 0.f, d = 0.f; int c = 0;
    if (tid < GROUPB) {
        for (int s = 0; s < NSL; ++s) {
            const char* sb = slices + (size_t)s * PER_SLICE;
            unsigned ab = ((const unsigned*)sb)[b];
            a += __half2float(__ushort_as_half((unsigned short)(ab & 0xFFFFu)));
            d += __half2float(__ushort_as_half((unsigned short)(ab >> 16)));
            c += ((const unsigned char*)(sb + 200000))[b];
        }
    }

    // prefix base from gsum (NFB=50 entries, wave 0)
    if (w == 0) {
        float gg = (lane < bid) ? gsum[lane] : 0.f;
        #pragma unroll
        for (int off = 32; off > 0; off >>= 1) gg += __shfl_down(gg, off, 64);
        if (lane == 0) sh_base = gg;
    }

    // in-block exclusive scan of a
    float x = a;
    #pragma unroll
    for (int off = 1; off < 64; off <<= 1) {
        float y = __shfl_up(x, off, 64);
        if (lane >= off) x += y;
    }
    if (lane == 63) wtot[w] = x;
    __syncthreads();
    float wb = 0.f;
    for (int i = 0; i < w; ++i) wb += wtot[i];
    float prefix = sh_base + wb + (x - a);         // risk over times strictly < t

    // Efron per-bin loss
    float acc = 0.f;
    if (tid < GROUPB && c > 0) {
        float D  = d;
        float nf = (float)c;
        float P  = D + (a - D) * (nf / (nf + 1.f));   // E[partial risk]
        float R  = prefix + P;
        for (int j = 0; j < c; ++j) {
            float arg = R - ((float)j / nf) * D + EPSF;
            acc += __logf(arg);
        }
    }
    #pragma unroll
    for (int off = 32; off > 0; off >>= 1) acc += __shfl_down(acc, off, 64);
    __syncthreads();
    if (lane == 0) red_f[w] = acc;
    __syncthreads();
    if (tid == 0) {
        float s = 0.f;
        #pragma unroll
        for (int i = 0; i < 16; ++i) s += red_f[i];
        atomicAdd(&scal[1], (double)s);
        __threadfence();
        int ticket = atomicAdd(done, 1);
        sh_last = (ticket == NFB - 1) ? 1 : 0;
    }
    __syncthreads();

    // last block finalizes: fold per-part-block scalars, write output
    if (sh_last) {
        float pl = (tid < NPB) ? lrp[tid] : 0.f;
        int   pn = (tid < NPB) ? np[tid]  : 0;
        #pragma unroll
        for (int off = 32; off > 0; off >>= 1) {
            pl += __shfl_down(pl, off, 64);
            pn += __shfl_down(pn, off, 64);
        }
        if (lane == 0) { red_f[w] = pl; red_i[w] = pn; }
        __syncthreads();
        if (tid == 0) {
            float s = 0.f; int n = 0;
            #pragma unroll
            for (int i = 0; i < 16; ++i) { s += red_f[i]; n += red_i[i]; }
            double logsum = atomicAdd(&scal[1], 0.0);   // coherent read of final sum
            out[0] = (n > 0) ? (float)((logsum - (double)s) / (double)n) : 0.f;
        }
    }
}

extern "C" void kernel_launch(void* const* d_in, const int* in_sizes, int n_in,
                              void* d_out, int out_size, void* d_ws, size_t ws_size,
                              hipStream_t stream) {
    const float* lr = (const float*)d_in[0];
    const int*   tm = (const int*)d_in[1];
    const int*   ev = (const int*)d_in[2];
    int N = in_sizes[0];

    char*     ws    = (char*)d_ws;
    double*   scal  = (double*)(ws + OFF_SCAL);
    int*      done  = (int*)(ws + OFF_DONE);
    float*    gsum  = (float*)(ws + OFF_GSUM);
    float*    lrp   = (float*)(ws + OFF_LRP);
    int*      np    = (int*)(ws + OFF_NP);
    unsigned* cnts  = (unsigned*)(ws + OFF_CNTS);
    unsigned* part  = (unsigned*)(ws + OFF_PART);

    // wave chunk, multiple of 256 elems; segment capacity = 2x mean (12-sigma safe)
    int WCH = (int)((((long long)N + (NPB * NWV) - 1) / (NPB * NWV) + 255) / 256) * 256;
    int CAP = ((WCH / 4 + 63) / 64) * 64;
    size_t part_bytes = (size_t)NPB * NWV * NR * CAP * 4;   // 33.5 MB at N=4.2M
    char* slices = ws + OFF_PART + part_bytes;              // NSL * PER_SLICE = 16.4 MB

    k_part<<<NPB, 1024, 0, stream>>>(lr, tm, ev, N, WCH, CAP, part, cnts, lrp, np,
                                     gsum, scal, done);
    k_pass<<<NR * NSL, 1024, 0, stream>>>(part, cnts, CAP, slices, gsum);
    k_final<<<NFB, 1024, 0, stream>>>(slices, gsum, lrp, np, scal, done,
                                      (float*)d_out);
}

// Round 13
// 75.205 us; speedup vs baseline: 1.4578x; 1.1404x over previous
//
#include <hip/hip_runtime.h>
#include <hip/hip_fp16.h>
#include <math.h>

#define TBINS   50000
#define NR      4
#define RBINS   12500          // TBINS / NR
#define GROUP   256
#define NGROUPS 196            // ceil(TBINS / GROUP)
#define EPSF    1e-7f
#define NPB     256            // partition blocks
#define NWV     16             // waves per partition block (1024 thr)
#define NSL     64             // pass slices (each covers NPB/NSL=4 part blocks)
#define PER_SLICE 256000       // u32 ab[TBINS] (200000) + u8 cnt[TBINS] (50000), padded

// ---- ws layout (byte offsets) ----
#define OFF_SCAL  0            // dbl[2]: [0]=sum lr over events, [1]=log-sum
#define OFF_NEV   16           // int
#define OFF_DONE  20           // int (k_loss finalize ticket)
#define OFF_GSUM  64           // f32[NGROUPS]
#define OFF_ALLG  2048         // f32[TBINS]
#define OFF_EVG   202048       // f32[TBINS]
#define OFF_CNTG  402048       // i32[TBINS]
#define OFF_LRP   602048       // f32[NPB]
#define OFF_NP    603072       // i32[NPB]
#define OFF_CNTS  604160       // u32[NPB*NWV*4]
#define OFF_PART  669696       // u32[NPB*NWV*4*WCH]

// ============ k_part: read raw once, pack+partition into per-(blk,wave,range) segments ============
__global__ __launch_bounds__(1024) void k_part(
        const float* __restrict__ lr, const int* __restrict__ tm,
        const int* __restrict__ ev, int N, int WCH,
        unsigned* __restrict__ part, unsigned* __restrict__ cnts,
        float* __restrict__ lrp, int* __restrict__ np) {
    __shared__ float red_f[16];
    __shared__ int   red_i[16];
    const int b = blockIdx.x, tid = threadIdx.x;
    const int w = tid >> 6, lane = tid & 63;
    const unsigned long long lmask = (1ULL << lane) - 1ULL;

    const int base0 = (b * NWV + w) * WCH;
    const unsigned seg0 = (unsigned)(b * NWV + w) * 4u;
    unsigned wc0 = 0, wc1 = 0, wc2 = 0, wc3 = 0;
    float l_lr = 0.f; int l_n = 0;

#define PART1(L, T, E, VALID) {                                           \
        float r_ = __expf(L);                                             \
        unsigned hb_ = (unsigned)__half_as_ushort(__float2half(r_));      \
        bool ve_ = (VALID) && ((E) != 0);                                 \
        if (ve_) { hb_ |= 0x8000u; l_lr += (L); l_n++; }                  \
        unsigned P_  = ((unsigned)(T) << 16) | hb_;                       \
        unsigned rg_ = ((unsigned)(T)) / 12500u;                          \
        { unsigned long long m_ = __ballot((VALID) && rg_ == 0u);         \
          if ((VALID) && rg_ == 0u)                                       \
              part[(size_t)(seg0 + 0u) * WCH + wc0 + (unsigned)__popcll(m_ & lmask)] = P_; \
          wc0 += (unsigned)__popcll(m_); }                                \
        { unsigned long long m_ = __ballot((VALID) && rg_ == 1u);         \
          if ((VALID) && rg_ == 1u)                                       \
              part[(size_t)(seg0 + 1u) * WCH + wc1 + (unsigned)__popcll(m_ & lmask)] = P_; \
          wc1 += (unsigned)__popcll(m_); }                                \
        { unsigned long long m_ = __ballot((VALID) && rg_ == 2u);         \
          if ((VALID) && rg_ == 2u)                                       \
              part[(size_t)(seg0 + 2u) * WCH + wc2 + (unsigned)__popcll(m_ & lmask)] = P_; \
          wc2 += (unsigned)__popcll(m_); }                                \
        { unsigned long long m_ = __ballot((VALID) && rg_ == 3u);         \
          if ((VALID) && rg_ == 3u)                                       \
              part[(size_t)(seg0 + 3u) * WCH + wc3 + (unsigned)__popcll(m_ & lmask)] = P_; \
          wc3 += (unsigned)__popcll(m_); }                                \
    }

    for (int it = 0; it < WCH; it += 256) {
        int idx = base0 + it + lane * 4;
        float4 l4 = {0.f, 0.f, 0.f, 0.f};
        int4   t4 = {0, 0, 0, 0};
        int4   e4 = {0, 0, 0, 0};
        if (idx + 3 < N) {
            l4 = *(const float4*)(lr + idx);
            t4 = *(const int4*)(tm + idx);
            e4 = *(const int4*)(ev + idx);
        } else if (idx < N) {
            float* lp = (float*)&l4; int* tp = (int*)&t4; int* ep = (int*)&e4;
            for (int k = 0; k < 4 && idx + k < N; ++k) {
                lp[k] = lr[idx + k]; tp[k] = tm[idx + k]; ep[k] = ev[idx + k];
            }
        }
        PART1(l4.x, t4.x, e4.x, (idx + 0) < N)
        PART1(l4.y, t4.y, e4.y, (idx + 1) < N)
        PART1(l4.z, t4.z, e4.z, (idx + 2) < N)
        PART1(l4.w, t4.w, e4.w, (idx + 3) < N)
    }

    if (lane == 0) {
        unsigned* c = cnts + seg0;
        c[0] = wc0; c[1] = wc1; c[2] = wc2; c[3] = wc3;
    }

    // block event scalars
    #pragma unroll
    for (int off = 32; off > 0; off >>= 1) {
        l_lr += __shfl_down(l_lr, off, 64);
        l_n  += __shfl_down(l_n,  off, 64);
    }
    if (lane == 0) { red_f[w] = l_lr; red_i[w] = l_n; }
    __syncthreads();
    if (tid == 0) {
        float s = 0.f; int c = 0;
        #pragma unroll
        for (int i = 0; i < NWV; ++i) { s += red_f[i]; c += red_i[i]; }
        lrp[b] = s; np[b] = c;
    }
}

// ============ k_pass: single-visit LDS histogram per (range, slice) ============
__global__ __launch_bounds__(1024) void k_pass(
        const unsigned* __restrict__ part, const unsigned* __restrict__ cnts,
        int WCH, char* __restrict__ slices) {
    __shared__ float    s_all[RBINS];
    __shared__ unsigned s_evcnt[RBINS];   // (count<<28) | fixed12.16(sum exp over events)
    const int bid = blockIdx.x;
    const int r = bid & 3, s = bid >> 2;
    const unsigned rbase = (unsigned)(r * RBINS);
    const int tid = threadIdx.x, w = tid >> 6, lane = tid & 63;

    for (int i = tid; i < RBINS; i += 1024) { s_all[i] = 0.f; s_evcnt[i] = 0u; }
    __syncthreads();

    // 64 segments feed this block: part-blocks [4s,4s+4) x 16 waves; wave w takes 4 of them
    for (int sl = w; sl < 4 * NWV; sl += NWV) {
        int pb = 4 * s + (sl >> 4);
        int pw = sl & 15;
        unsigned seg = (unsigned)(pb * NWV + pw) * 4u + (unsigned)r;
        unsigned cnt = cnts[seg];
        const unsigned* sp = part + (size_t)seg * WCH;
        for (unsigned i = (unsigned)lane; i < cnt; i += 64u) {
            unsigned P = sp[i];
            unsigned rel = (P >> 16) - rbase;
            if (rel < (unsigned)RBINS) {
                float r_ = __half2float(__ushort_as_half((unsigned short)(P & 0x7FFFu)));
                atomicAdd(&s_all[rel], r_);
                if (P & 0x8000u) {
                    unsigned enc = (1u << 28) + (unsigned)(r_ * 65536.0f + 0.5f);
                    atomicAdd(&s_evcnt[rel], enc);
                }
            }
        }
    }
    __syncthreads();

    // flush: f16(all)|f16(ev) + u8 count
    char* sb = slices + (size_t)s * PER_SLICE;
    unsigned*      wab = (unsigned*)sb;
    unsigned char* wcq = (unsigned char*)(sb + 200000);
    for (int i = tid; i < RBINS; i += 1024) {
        float a = s_all[i];
        unsigned ec = s_evcnt[i];
        float e = (float)(ec & 0x0FFFFFFFu) * (1.0f / 65536.0f);
        wab[rbase + i] = (unsigned)__half_as_ushort(__float2half(a))
                       | ((unsigned)__half_as_ushort(__float2half(e)) << 16);
        wcq[rbase + i] = (unsigned char)(ec >> 28);
    }
}

// ============ k_reduce: fold NSL slices; gsum; block 0 folds scalars + inits ============
__global__ __launch_bounds__(256) void k_reduce(const char* __restrict__ slices,
                                                const float* __restrict__ lrp,
                                                const int* __restrict__ np,
                                                float* all_g, float* ev_g, int* cnt_g,
                                                float* gsum, double* scal, int* nev,
                                                int* done) {
    __shared__ float lds[4];
    __shared__ float ldsf2[4];
    __shared__ int   ldsi2[4];
    int tid = threadIdx.x;
    int b = blockIdx.x * 256 + tid;
    float a = 0.f, d = 0.f; int c = 0;
    if (b < TBINS) {
        for (int s = 0; s < NSL; ++s) {
            const char* sb = slices + (size_t)s * PER_SLICE;
            unsigned ab = ((const unsigned*)sb)[b];
            a += __half2float(__ushort_as_half((unsigned short)(ab & 0xFFFFu)));
            d += __half2float(__ushort_as_half((unsigned short)(ab >> 16)));
            c += ((const unsigned char*)(sb + 200000))[b];
        }
        all_g[b] = a; ev_g[b] = d; cnt_g[b] = c;
    }
    int lane = tid & 63, wv = tid >> 6;
    float v = a;
    #pragma unroll
    for (int off = 32; off > 0; off >>= 1) v += __shfl_down(v, off, 64);
    if (lane == 0) lds[wv] = v;
    __syncthreads();
    if (tid == 0) {
        float s = 0.f;
        #pragma unroll
        for (int w = 0; w < 4; ++w) s += lds[w];
        gsum[blockIdx.x] = s;
    }

    if (blockIdx.x == 0) {
        float pl = lrp[tid];      // NPB == 256 == blockDim
        int   pn = np[tid];
        #pragma unroll
        for (int off = 32; off > 0; off >>= 1) {
            pl += __shfl_down(pl, off, 64);
            pn += __shfl_down(pn, off, 64);
        }
        if (lane == 0) { ldsf2[wv] = pl; ldsi2[wv] = pn; }
        __syncthreads();
        if (tid == 0) {
            float s = 0.f; int n = 0;
            #pragma unroll
            for (int w = 0; w < 4; ++w) { s += ldsf2[w]; n += ldsi2[w]; }
            scal[0] = (double)s;
            scal[1] = 0.0;
            *nev    = n;
            *done   = 0;
        }
    }
}

// ============ k_loss: prefix-scan + Efron loss; last block finalizes ============
__global__ __launch_bounds__(256) void k_loss(
        const float* __restrict__ all_g, const float* __restrict__ gsum,
        const int* __restrict__ cnt_g, const float* __restrict__ ev_g,
        double* scal, const int* __restrict__ nev, int* done,
        float* __restrict__ out) {
    __shared__ float lds_r[4];
    __shared__ float lds_s[4];
    __shared__ float sh_base;
    int b   = blockIdx.x;
    int tid = threadIdx.x;
    int t   = b * GROUP + tid;
    int lane = tid & 63, wv = tid >> 6;

    float gv = (tid < b) ? gsum[tid] : 0.f;   // b <= 195 < 256
    float red = gv;
    #pragma unroll
    for (int off = 32; off > 0; off >>= 1) red += __shfl_down(red, off, 64);
    if (lane == 0) lds_r[wv] = red;
    __syncthreads();
    if (tid == 0) {
        float s = 0.f;
        #pragma unroll
        for (int w = 0; w < 4; ++w) s += lds_r[w];
        sh_base = s;
    }
    __syncthreads();
    float base = sh_base;

    float v = (t < TBINS) ? all_g[t] : 0.f;
    float x = v;
    #pragma unroll
    for (int off = 1; off < 64; off <<= 1) {
        float y = __shfl_up(x, off, 64);
        if (lane >= off) x += y;
    }
    if (lane == 63) lds_s[wv] = x;
    __syncthreads();
    float wb = 0.f;
    for (int w = 0; w < wv; ++w) wb += lds_s[w];
    float prefix = base + wb + (x - v);       // risk over times strictly < t

    float acc = 0.f;
    if (t < TBINS) {
        int n = cnt_g[t];
        if (n > 0) {
            float D  = ev_g[t];
            float nf = (float)n;
            float P  = D + (v - D) * (nf / (nf + 1.f));   // E[partial risk]
            float R  = prefix + P;
            for (int j = 0; j < n; ++j) {
                float arg = R - ((float)j / nf) * D + EPSF;
                acc += __logf(arg);
            }
        }
    }
    __syncthreads();
    #pragma unroll
    for (int off = 32; off > 0; off >>= 1) acc += __shfl_down(acc, off, 64);
    if (lane == 0) lds_r[wv] = acc;
    __syncthreads();
    if (tid == 0) {
        float s = 0.f;
        #pragma unroll
        for (int w = 0; w < 4; ++w) s += lds_r[w];
        atomicAdd(&scal[1], (double)s);
        __threadfence();
        int ticket = atomicAdd(done, 1);
        if (ticket == NGROUPS - 1) {
            double logsum = atomicAdd(&scal[1], 0.0);   // coherent read of final sum
            int n = *nev;
            out[0] = (n > 0) ? (float)((logsum - scal[0]) / (double)n) : 0.f;
        }
    }
}

extern "C" void kernel_launch(void* const* d_in, const int* in_sizes, int n_in,
                              void* d_out, int out_size, void* d_ws, size_t ws_size,
                              hipStream_t stream) {
    const float* lr = (const float*)d_in[0];
    const int*   tm = (const int*)d_in[1];
    const int*   ev = (const int*)d_in[2];
    int N = in_sizes[0];

    char*     ws    = (char*)d_ws;
    double*   scal  = (double*)(ws + OFF_SCAL);
    int*      nev   = (int*)(ws + OFF_NEV);
    int*      done  = (int*)(ws + OFF_DONE);
    float*    gsum  = (float*)(ws + OFF_GSUM);
    float*    all_g = (float*)(ws + OFF_ALLG);
    float*    ev_g  = (float*)(ws + OFF_EVG);
    int*      cnt_g = (int*)(ws + OFF_CNTG);
    float*    lrp   = (float*)(ws + OFF_LRP);
    int*      np    = (int*)(ws + OFF_NP);
    unsigned* cnts  = (unsigned*)(ws + OFF_CNTS);
    unsigned* part  = (unsigned*)(ws + OFF_PART);

    // wave chunk, multiple of 256 elems
    int WCH = (int)((((long long)N + (NPB * NWV) - 1) / (NPB * NWV) + 255) / 256) * 256;
    size_t part_bytes = (size_t)NPB * NWV * 4 * WCH * 4;
    char* slices = ws + OFF_PART + part_bytes;   // NSL * PER_SLICE = 16.4 MB

    k_part<<<NPB, 1024, 0, stream>>>(lr, tm, ev, N, WCH, part, cnts, lrp, np);
    k_pass<<<NR * NSL, 1024, 0, stream>>>(part, cnts, WCH, slices);
    k_reduce<<<NGROUPS, 256, 0, stream>>>(slices, lrp, np, all_g, ev_g, cnt_g,
                                          gsum, scal, nev, done);
    k_loss<<<NGROUPS, 256, 0, stream>>>(all_g, gsum, cnt_g, ev_g, scal, nev, done,
                                        (float*)d_out);
}